// Round 5
// baseline (61.881 us; speedup 1.0000x reference)
//
#include <hip/hip_runtime.h>
#include <math.h>

#define NB 256
#define NH 224
#define NW 224
#define HW (NH * NW)          // 50176
#define CHW (3 * HW)          // 150528
#define GP 4                  // pixels per thread-tile
#define NT 256                // threads per block (4 waves)
#define WGR (NW / GP)         // 56 pixel-groups per row
#define GPI (HW / GP)         // 12544 groups per image
#define BPI (GPI / NT)        // 49 virtual blocks per image
#define NVB (NB * BPI)        // 12544 virtual blocks
#define PERSIST 2048          // 8 blocks/CU * 256 CU -> persistent grid

struct Params {
    float b255;               // b_fac / 255
    float k1;                 // c_fac * s_fac * cos_h
    float k2;                 // c_fac * s_fac * sin_h * 0.5
    int   flip, apply, top, left, he, we;
};

// Per-image scalars, computed redundantly per-thread (uniform -> s_loads, no LDS,
// no barrier). Erase-box integers MUST be bit-exact vs the fp32 reference ->
// no FMA contraction here, expression order mirrors the reference.
__device__ __forceinline__ Params make_params(int b,
    const float* __restrict__ flip_u, const float* __restrict__ bj_u,
    const float* __restrict__ cj_u,   const float* __restrict__ sj_u,
    const float* __restrict__ hue_u,  const float* __restrict__ erase_u,
    const float* __restrict__ area_u, const float* __restrict__ aspect_u,
    const float* __restrict__ top_u,  const float* __restrict__ left_u)
{
#pragma clang fp contract(off)
    Params p;
    p.flip = (flip_u[b] > 0.5f) ? 1 : 0;
    float b_fac = 1.0f + (bj_u[b] * 2.0f - 1.0f) * 0.4f;
    float c_fac = 1.0f + (cj_u[b] * 2.0f - 1.0f) * 0.4f;
    float s_fac = 1.0f + (sj_u[b] * 2.0f - 1.0f) * 0.4f;
    float h_fac = (hue_u[b] * 2.0f - 1.0f) * 0.1f * 0.5f;
    float ang   = h_fac * 3.14159f;
    // contrast+saturation preserve the per-pixel mean -> whole color chain is
    // one affine map about one gray: out_c = gray + k1*(c-gray) + k2*cross_c
    float cs = c_fac * s_fac;
    p.b255 = b_fac * (1.0f / 255.0f);
    p.k1   = cs * cosf(ang);
    p.k2   = cs * sinf(ang) * 0.5f;

    float ta     = (0.02f + area_u[b] * 0.31f) * (float)HW;
    float aspect = 0.3f + aspect_u[b] * 3.0f;
    int he = (int)rintf(sqrtf(ta * aspect));   // jnp.round = half-even = rintf
    int we = (int)rintf(sqrtf(ta / aspect));
    p.apply = (erase_u[b] < 0.25f) && (he < NH) && (we < NW);
    int th = NH - he + 1; if (th < 1) th = 1;
    int tw = NW - we + 1; if (tw < 1) tw = 1;
    p.top  = (int)floorf(top_u[b]  * (float)th);
    p.left = (int)floorf(left_u[b] * (float)tw);
    p.he = he; p.we = we;
    return p;
}

__global__ __launch_bounds__(NT) void aug_kernel(
    const int*   __restrict__ x,
    const float* __restrict__ flip_u, const float* __restrict__ bj_u,
    const float* __restrict__ cj_u,   const float* __restrict__ sj_u,
    const float* __restrict__ hue_u,  const float* __restrict__ erase_u,
    const float* __restrict__ area_u, const float* __restrict__ aspect_u,
    const float* __restrict__ top_u,  const float* __restrict__ left_u,
    const float* __restrict__ noise,  const float* __restrict__ mean,
    const float* __restrict__ stdv,
    float* __restrict__ out)
{
    // normalization constants (uniform, loaded once)
    const float i0 = 1.0f / stdv[0], i1 = 1.0f / stdv[1], i2 = 1.0f / stdv[2];
    const float mi0 = mean[0] * i0, mi1 = mean[1] * i1, mi2 = mean[2] * i2;
    const float third = 1.0f / 3.0f;
    const int tid = threadIdx.x;

    // ---- geometry helper (all compile-time-constant divisors) ----
    auto geom = [&](unsigned vb, int flip, int& base, int& w4, int& h, int& srcw4) {
        unsigned bimg = vb / BPI;
        unsigned rblk = vb - bimg * BPI;
        unsigned r  = rblk * NT + tid;
        h  = (int)(r / WGR);
        w4 = (int)(r - (unsigned)h * WGR) * GP;
        base  = (int)bimg * CHW + h * NW;
        srcw4 = flip ? (NW - GP - w4) : w4;
    };

    // ---- prologue: params + loads for first virtual block ----
    unsigned vb = blockIdx.x;
    unsigned bimg = vb / BPI;
    Params p = make_params((int)bimg, flip_u, bj_u, cj_u, sj_u, hue_u,
                           erase_u, area_u, aspect_u, top_u, left_u);
    int base, w4, h, srcw4;
    geom(vb, p.flip, base, w4, h, srcw4);
    int4 xi0 = *(const int4*)(x + base          + srcw4);
    int4 xi1 = *(const int4*)(x + base + HW     + srcw4);
    int4 xi2 = *(const int4*)(x + base + 2*HW   + srcw4);

    for (;;) {
        // ---- stage next iteration: params + issue loads early ----
        unsigned vbn = vb + PERSIST;
        const bool last = (vbn >= NVB);
        unsigned vbn_c = last ? vb : vbn;
        unsigned bimg_n = vbn_c / BPI;
        Params pn = make_params((int)bimg_n, flip_u, bj_u, cj_u, sj_u, hue_u,
                                erase_u, area_u, aspect_u, top_u, left_u);
        int base_n, w4_n, h_n, srcw4_n;
        geom(vbn_c, pn.flip, base_n, w4_n, h_n, srcw4_n);
        int4 yi0 = *(const int4*)(x + base_n          + srcw4_n);
        int4 yi1 = *(const int4*)(x + base_n + HW     + srcw4_n);
        int4 yi2 = *(const int4*)(x + base_n + 2*HW   + srcw4_n);

        // ---- compute + store current ----
        {
            const float b255 = p.b255, k1 = p.k1, k2 = p.k2;
            const int* p0 = (const int*)&xi0;
            const int* p1 = (const int*)&xi1;
            const int* p2 = (const int*)&xi2;
            float v[3][GP];
            #pragma unroll
            for (int i = 0; i < GP; ++i) {
                const int src = p.flip ? (GP - 1 - i) : i;
                float r_ = (float)p0[src] * b255;     // brightness folded in /255
                float g_ = (float)p1[src] * b255;
                float b_ = (float)p2[src] * b255;

                float gray = (r_ + g_ + b_) * third;
                float rn = fmaf(k2, g_ - b_, fmaf(k1, r_ - gray, gray));
                float gn = fmaf(k2, b_ - r_, fmaf(k1, g_ - gray, gray));
                float bn = fmaf(k2, r_ - g_, fmaf(k1, b_ - gray, gray));

                rn = fminf(fmaxf(rn, 0.0f), 1.0f);    // v_med3
                gn = fminf(fmaxf(gn, 0.0f), 1.0f);
                bn = fminf(fmaxf(bn, 0.0f), 1.0f);

                v[0][i] = fmaf(rn, i0, -mi0);
                v[1][i] = fmaf(gn, i1, -mi1);
                v[2][i] = fmaf(bn, i2, -mi2);
            }

            const bool rowin = p.apply && (h >= p.top) && (h < p.top + p.he);
            if (rowin) {
                #pragma unroll
                for (int i = 0; i < GP; ++i) {
                    const int col = w4 + i;
                    if (col >= p.left && col < p.left + p.we) {
                        v[0][i] = noise[base          + col];
                        v[1][i] = noise[base + HW     + col];
                        v[2][i] = noise[base + 2*HW   + col];
                    }
                }
            }

            *(float4*)(out + base          + w4) = make_float4(v[0][0], v[0][1], v[0][2], v[0][3]);
            *(float4*)(out + base + HW     + w4) = make_float4(v[1][0], v[1][1], v[1][2], v[1][3]);
            *(float4*)(out + base + 2*HW   + w4) = make_float4(v[2][0], v[2][1], v[2][2], v[2][3]);
        }

        if (last) break;
        vb = vbn; p = pn;
        base = base_n; w4 = w4_n; h = h_n;
        xi0 = yi0; xi1 = yi1; xi2 = yi2;
    }
}

extern "C" void kernel_launch(void* const* d_in, const int* in_sizes, int n_in,
                              void* d_out, int out_size, void* d_ws, size_t ws_size,
                              hipStream_t stream) {
    const int*   x        = (const int*)  d_in[0];
    const float* flip_u   = (const float*)d_in[1];
    const float* bj_u     = (const float*)d_in[2];
    const float* cj_u     = (const float*)d_in[3];
    const float* sj_u     = (const float*)d_in[4];
    const float* hue_u    = (const float*)d_in[5];
    const float* erase_u  = (const float*)d_in[6];
    const float* area_u   = (const float*)d_in[7];
    const float* aspect_u = (const float*)d_in[8];
    const float* top_u    = (const float*)d_in[9];
    const float* left_u   = (const float*)d_in[10];
    const float* noise    = (const float*)d_in[11];
    const float* mean     = (const float*)d_in[12];
    const float* stdv     = (const float*)d_in[13];
    float* out = (float*)d_out;

    aug_kernel<<<PERSIST, NT, 0, stream>>>(x, flip_u, bj_u, cj_u, sj_u, hue_u,
                                           erase_u, area_u, aspect_u, top_u, left_u,
                                           noise, mean, stdv, out);
}

// Round 6
// 57.284 us; speedup vs baseline: 1.0802x; 1.0802x over previous
//
#include <hip/hip_runtime.h>
#include <math.h>

#define NB 256
#define NH 224
#define NW 224
#define HW (NH * NW)          // 50176
#define CHW (3 * HW)          // 150528
#define GP 4                  // pixels per thread
#define NT 256                // threads per block (4 waves)
#define WGR (NW / GP)         // 56 pixel-groups per row
#define GPI (HW / GP)         // 12544 groups per image
#define BPI (GPI / NT)        // 49 blocks per image

__global__ __launch_bounds__(NT) void aug_kernel(
    const int*   __restrict__ x,
    const float* __restrict__ flip_u, const float* __restrict__ bj_u,
    const float* __restrict__ cj_u,   const float* __restrict__ sj_u,
    const float* __restrict__ hue_u,  const float* __restrict__ erase_u,
    const float* __restrict__ area_u, const float* __restrict__ aspect_u,
    const float* __restrict__ top_u,  const float* __restrict__ left_u,
    const float* __restrict__ noise,  const float* __restrict__ mean,
    const float* __restrict__ stdv,
    float* __restrict__ out)
{
    const int bimg = blockIdx.x / BPI;

    // ---- 1) the ONLY scalar the x-loads depend on: flip ----
    const int flip = (flip_u[bimg] > 0.5f) ? 1 : 0;

    // ---- 2) geometry + issue the 3 main loads immediately ----
    const int r  = (blockIdx.x % BPI) * NT + threadIdx.x;  // 4-px group in image
    const int h  = r / WGR;
    const int w4 = (r - h * WGR) * GP;
    const int base  = bimg * CHW + h * NW;                 // fits in int32
    const int srcw4 = flip ? (NW - GP - w4) : w4;          // stays 16B-aligned

    int4 xi0 = *(const int4*)(x + base          + srcw4);
    int4 xi1 = *(const int4*)(x + base + HW     + srcw4);
    int4 xi2 = *(const int4*)(x + base + 2*HW   + srcw4);

    // ---- 3) rest of the per-image params, overlapped with the loads ----
    // Color factors (tolerance-safe algebraic fusion): contrast+saturation
    // preserve the per-pixel mean, so the whole color chain is one affine map
    // about one gray: out_c = gray + k1*(c-gray) + k2*cross_c.
    float b255, k1, k2;
    int apply, top, left, he, we;
    {
#pragma clang fp contract(off)
        // Erase-box integers MUST be bit-exact vs the fp32 reference ->
        // no FMA contraction, expression order mirrors the reference.
        float b_fac = 1.0f + (bj_u[bimg] * 2.0f - 1.0f) * 0.4f;
        float c_fac = 1.0f + (cj_u[bimg] * 2.0f - 1.0f) * 0.4f;
        float s_fac = 1.0f + (sj_u[bimg] * 2.0f - 1.0f) * 0.4f;
        float h_fac = (hue_u[bimg] * 2.0f - 1.0f) * 0.1f * 0.5f;
        float ang   = h_fac * 3.14159f;
        float cs    = c_fac * s_fac;
        b255 = b_fac * (1.0f / 255.0f);
        k1   = cs * cosf(ang);
        k2   = cs * sinf(ang) * 0.5f;

        float ta     = (0.02f + area_u[bimg] * 0.31f) * (float)HW;
        float aspect = 0.3f + aspect_u[bimg] * 3.0f;
        he = (int)rintf(sqrtf(ta * aspect));   // jnp.round = half-even = rintf
        we = (int)rintf(sqrtf(ta / aspect));
        apply = (erase_u[bimg] < 0.25f) && (he < NH) && (we < NW);
        int th = NH - he + 1; if (th < 1) th = 1;
        int tw = NW - we + 1; if (tw < 1) tw = 1;
        top  = (int)floorf(top_u[bimg]  * (float)th);
        left = (int)floorf(left_u[bimg] * (float)tw);
    }

    // normalization constants (uniform, hot in cache)
    const float i0 = 1.0f / stdv[0], i1 = 1.0f / stdv[1], i2 = 1.0f / stdv[2];
    const float mi0 = mean[0] * i0, mi1 = mean[1] * i1, mi2 = mean[2] * i2;
    const float third = 1.0f / 3.0f;

    // ---- 4) compute ----
    float v[3][GP];
    {
        const int* p0 = (const int*)&xi0;
        const int* p1 = (const int*)&xi1;
        const int* p2 = (const int*)&xi2;
        #pragma unroll
        for (int i = 0; i < GP; ++i) {
            const int src = flip ? (GP - 1 - i) : i;
            float r_ = (float)p0[src] * b255;     // brightness folded into /255
            float g_ = (float)p1[src] * b255;
            float b_ = (float)p2[src] * b255;

            float gray = (r_ + g_ + b_) * third;
            float rn = fmaf(k2, g_ - b_, fmaf(k1, r_ - gray, gray));
            float gn = fmaf(k2, b_ - r_, fmaf(k1, g_ - gray, gray));
            float bn = fmaf(k2, r_ - g_, fmaf(k1, b_ - gray, gray));

            rn = fminf(fmaxf(rn, 0.0f), 1.0f);    // v_med3
            gn = fminf(fmaxf(gn, 0.0f), 1.0f);
            bn = fminf(fmaxf(bn, 0.0f), 1.0f);

            v[0][i] = fmaf(rn, i0, -mi0);
            v[1][i] = fmaf(gn, i1, -mi1);
            v[2][i] = fmaf(bn, i2, -mi2);
        }
    }

    // ---- 5) random erase ----
    const bool rowin = apply && (h >= top) && (h < top + he);
    if (rowin) {
        #pragma unroll
        for (int i = 0; i < GP; ++i) {
            const int col = w4 + i;
            if (col >= left && col < left + we) {
                v[0][i] = noise[base          + col];
                v[1][i] = noise[base + HW     + col];
                v[2][i] = noise[base + 2*HW   + col];
            }
        }
    }

    // ---- 6) store ----
    *(float4*)(out + base          + w4) = make_float4(v[0][0], v[0][1], v[0][2], v[0][3]);
    *(float4*)(out + base + HW     + w4) = make_float4(v[1][0], v[1][1], v[1][2], v[1][3]);
    *(float4*)(out + base + 2*HW   + w4) = make_float4(v[2][0], v[2][1], v[2][2], v[2][3]);
}

extern "C" void kernel_launch(void* const* d_in, const int* in_sizes, int n_in,
                              void* d_out, int out_size, void* d_ws, size_t ws_size,
                              hipStream_t stream) {
    const int*   x        = (const int*)  d_in[0];
    const float* flip_u   = (const float*)d_in[1];
    const float* bj_u     = (const float*)d_in[2];
    const float* cj_u     = (const float*)d_in[3];
    const float* sj_u     = (const float*)d_in[4];
    const float* hue_u    = (const float*)d_in[5];
    const float* erase_u  = (const float*)d_in[6];
    const float* area_u   = (const float*)d_in[7];
    const float* aspect_u = (const float*)d_in[8];
    const float* top_u    = (const float*)d_in[9];
    const float* left_u   = (const float*)d_in[10];
    const float* noise    = (const float*)d_in[11];
    const float* mean     = (const float*)d_in[12];
    const float* stdv     = (const float*)d_in[13];
    float* out = (float*)d_out;

    const int grid = NB * BPI;   // 256 images * 49 blocks = 12544
    aug_kernel<<<grid, NT, 0, stream>>>(x, flip_u, bj_u, cj_u, sj_u, hue_u,
                                        erase_u, area_u, aspect_u, top_u, left_u,
                                        noise, mean, stdv, out);
}